// Round 8
// baseline (329.109 us; speedup 1.0000x reference)
//
#include <hip/hip_runtime.h>
#include <math.h>

#define N_NODES 100000
#define N_EDGES 1600000
#define OUT_F   64
#define NCHUNK  98                      // ceil(N_NODES / 1024)

#define EQ4      (N_EDGES / 4)          // 400000 quads
#define CNT_BLK  ((EQ4 + 255) / 256)    // 1563
#define GEMM_BLK 512
#define K_E      18                     // max 18432 edges/chunk

typedef __attribute__((ext_vector_type(8))) short bf16x8;
typedef __attribute__((ext_vector_type(4))) float f32x4;

__device__ __forceinline__ unsigned short f2bf_rne(float f) {
    unsigned u = __float_as_uint(f);
    return (unsigned short)((u + 0x7fffu + ((u >> 16) & 1u)) >> 16);
}
__device__ __forceinline__ float bf2f(unsigned short h) {
    return __uint_as_float((unsigned)h << 16);
}

// ---------------------------------------------------------------------------
// K1: blocks [0, CNT_BLK): LDS 98-bin histogram of dst>>10 -> pcnt[block][*].
//     blocks [CNT_BLK, ...): MFMA GEMM G = feat @ W_h; first GEMM block also
//     zeroes the colscan 'done' flag (visible at next dispatch).
// ---------------------------------------------------------------------------
__global__ __launch_bounds__(256) void count_gemm(
    const int* __restrict__ dst, unsigned* __restrict__ pcnt,
    const float* __restrict__ feat, const float* __restrict__ weight,
    unsigned short* __restrict__ G, unsigned* __restrict__ done)
{
    __shared__ unsigned lbin[NCHUNK];
    int tid = threadIdx.x;

    if (blockIdx.x < CNT_BLK) {
        if (tid < NCHUNK) lbin[tid] = 0u;
        __syncthreads();
        int q = blockIdx.x * 256 + tid;
        if (q < EQ4) {
            int4 d = ((const int4*)dst)[q];
            atomicAdd(&lbin[d.x >> 10], 1u);
            atomicAdd(&lbin[d.y >> 10], 1u);
            atomicAdd(&lbin[d.z >> 10], 1u);
            atomicAdd(&lbin[d.w >> 10], 1u);
        }
        __syncthreads();
        if (tid < NCHUNK)
            pcnt[(size_t)blockIdx.x * NCHUNK + tid] = lbin[tid];
        return;
    }

    int gb = (int)blockIdx.x - CNT_BLK;
    if (gb == 0 && tid == 0) *done = 0u;

    int wv = tid >> 6, ln = tid & 63;
    int li = ln & 15, lk = ln >> 4;

    bf16x8 Whi[4][2], Wlo[4][2];
    #pragma unroll
    for (int it = 0; it < 4; ++it)
        #pragma unroll
        for (int kb = 0; kb < 2; ++kb)
            #pragma unroll
            for (int j = 0; j < 8; ++j) {
                float w = weight[(16 + kb * 32 + lk * 8 + j) * 64 + it * 16 + li];
                unsigned short h = f2bf_rne(w);
                Whi[it][kb][j] = (short)h;
                Wlo[it][kb][j] = (short)f2bf_rne(w - bf2f(h));
            }

    const int tiles = N_NODES / 16;   // 6250 exact
    for (int tile = gb * 4 + wv; tile < tiles; tile += GEMM_BLK * 4) {
        int n = tile * 16 + li;
        const float* fr = feat + (size_t)n * 64 + lk * 8;

        bf16x8 Bhi[2], Blo[2];
        #pragma unroll
        for (int kb = 0; kb < 2; ++kb) {
            float4 v0 = *(const float4*)(fr + kb * 32);
            float4 v1 = *(const float4*)(fr + kb * 32 + 4);
            float vv[8] = {v0.x, v0.y, v0.z, v0.w, v1.x, v1.y, v1.z, v1.w};
            #pragma unroll
            for (int j = 0; j < 8; ++j) {
                unsigned short h = f2bf_rne(vv[j]);
                Bhi[kb][j] = (short)h;
                Blo[kb][j] = (short)f2bf_rne(vv[j] - bf2f(h));
            }
        }

        f32x4 acc[4] = {{0.f,0.f,0.f,0.f},{0.f,0.f,0.f,0.f},
                        {0.f,0.f,0.f,0.f},{0.f,0.f,0.f,0.f}};
        #pragma unroll
        for (int kb = 0; kb < 2; ++kb)
            #pragma unroll
            for (int it = 0; it < 4; ++it) {
                acc[it] = __builtin_amdgcn_mfma_f32_16x16x32_bf16(Whi[it][kb], Bhi[kb], acc[it], 0, 0, 0);
                acc[it] = __builtin_amdgcn_mfma_f32_16x16x32_bf16(Wlo[it][kb], Bhi[kb], acc[it], 0, 0, 0);
                acc[it] = __builtin_amdgcn_mfma_f32_16x16x32_bf16(Whi[it][kb], Blo[kb], acc[it], 0, 0, 0);
            }

        #pragma unroll
        for (int it = 0; it < 4; ++it) {
            ushort4 o;
            o.x = f2bf_rne(acc[it][0]);
            o.y = f2bf_rne(acc[it][1]);
            o.z = f2bf_rne(acc[it][2]);
            o.w = f2bf_rne(acc[it][3]);
            *(ushort4*)(G + (size_t)n * 64 + it * 16 + lk * 4) = o;
        }
    }
}

// ---------------------------------------------------------------------------
// K2: per-chunk column scan of pcnt -> pbase + ctot; the LAST block to finish
// (device-scope done counter) also scans ctot -> cbase. scan98 dispatch gone.
// ---------------------------------------------------------------------------
__global__ __launch_bounds__(1024) void colscan_cbase(
    const unsigned* __restrict__ pcnt, unsigned* __restrict__ pbase,
    unsigned* __restrict__ ctot, unsigned* __restrict__ cbase,
    unsigned* __restrict__ done)
{
    __shared__ unsigned ws[16];
    __shared__ unsigned isLast;
    int c = blockIdx.x, t = threadIdx.x;
    unsigned j0 = 2u * (unsigned)t, j1 = j0 + 1u;
    unsigned v0 = (j0 < CNT_BLK) ? pcnt[(size_t)j0 * NCHUNK + c] : 0u;
    unsigned v1 = (j1 < CNT_BLK) ? pcnt[(size_t)j1 * NCHUNK + c] : 0u;
    unsigned s = v0 + v1;
    unsigned x = s;
    #pragma unroll
    for (int o = 1; o < 64; o <<= 1) {
        unsigned u = __shfl_up(x, o);
        if ((t & 63) >= o) x += u;
    }
    if ((t & 63) == 63) ws[t >> 6] = x;
    __syncthreads();
    if (t < 16) {
        unsigned y = ws[t];
        #pragma unroll
        for (int o = 1; o < 16; o <<= 1) {
            unsigned u = __shfl_up(y, o);
            if (t >= o) y += u;
        }
        ws[t] = y;
    }
    __syncthreads();
    unsigned excl = ((t >> 6) ? ws[(t >> 6) - 1] : 0u) + x - s;
    if (j0 < CNT_BLK) pbase[(size_t)j0 * NCHUNK + c] = excl;
    if (j1 < CNT_BLK) pbase[(size_t)j1 * NCHUNK + c] = excl + v0;
    if (t == 1023) ctot[c] = excl + s;

    // ---- last-done block: exclusive scan ctot[98] -> cbase ----
    __threadfence();
    if (t == 0) isLast = (atomicAdd(done, 1u) == NCHUNK - 1u) ? 1u : 0u;
    __syncthreads();
    if (!isLast) return;

    int ln = t & 63, wv = t >> 6;
    unsigned v = (t < NCHUNK) ? atomicAdd(&ctot[t], 0u) : 0u;  // coherent read
    unsigned y = v;
    #pragma unroll
    for (int o = 1; o < 64; o <<= 1) {
        unsigned u = __shfl_up(y, o);
        if (ln >= o) y += u;
    }
    if (ln == 63) ws[wv] = y;
    __syncthreads();
    unsigned base = (wv == 1) ? ws[0] : 0u;
    if (t < NCHUNK) cbase[t] = base + y - v;
}

// ---------------------------------------------------------------------------
// K3: scatter — ranks via LDS atomics; block's 1024 edges STAGED IN LDS in
// chunk order (block-local scan of cnt gives layout), then written out
// linearly: consecutive lanes -> consecutive addresses within segment runs
// (~8x fewer cache-line transactions per store than direct per-lane scatter).
// Entry: lo = src | (dst&1023)<<20, hi = edge_id.
// ---------------------------------------------------------------------------
__global__ __launch_bounds__(256) void scatter(
    const int* __restrict__ src, const int* __restrict__ dst,
    const unsigned* __restrict__ pbase, const unsigned* __restrict__ cbase,
    unsigned long long* __restrict__ csr_pack)
{
    __shared__ unsigned cnt[NCHUNK];
    __shared__ unsigned gbs[NCHUNK];
    __shared__ unsigned lbase[NCHUNK];
    __shared__ unsigned wsum[4];
    __shared__ unsigned long long sval[1024];
    __shared__ unsigned sadr[1024];
    int tid = threadIdx.x, wv = tid >> 6, ln = tid & 63;

    if (tid < NCHUNK) cnt[tid] = 0u;
    __syncthreads();

    int q = blockIdx.x * 256 + tid;
    bool act = q < EQ4;
    int4 d = {0,0,0,0}, s = {0,0,0,0};
    unsigned r0 = 0, r1 = 0, r2 = 0, r3 = 0;
    if (act) {
        d = ((const int4*)dst)[q];
        s = ((const int4*)src)[q];
        r0 = atomicAdd(&cnt[d.x >> 10], 1u);
        r1 = atomicAdd(&cnt[d.y >> 10], 1u);
        r2 = atomicAdd(&cnt[d.z >> 10], 1u);
        r3 = atomicAdd(&cnt[d.w >> 10], 1u);
    }
    if (tid < NCHUNK)
        gbs[tid] = cbase[tid] + pbase[(size_t)blockIdx.x * NCHUNK + tid];
    __syncthreads();

    // exclusive scan of cnt[0..97] (waves 0-1 carry data; others scan zeros)
    unsigned v = (tid < NCHUNK) ? cnt[tid] : 0u;
    unsigned x = v;
    #pragma unroll
    for (int o = 1; o < 64; o <<= 1) {
        unsigned u = __shfl_up(x, o);
        if (ln >= o) x += u;
    }
    if (ln == 63) wsum[wv] = x;
    __syncthreads();
    unsigned excl = x - v + ((wv == 1) ? wsum[0] : 0u);
    unsigned tot = wsum[0] + wsum[1];
    if (tid < NCHUNK) lbase[tid] = excl;
    __syncthreads();

    if (act) {
        unsigned e = (unsigned)q * 4u;
        unsigned c0 = (unsigned)d.x >> 10, c1 = (unsigned)d.y >> 10;
        unsigned c2 = (unsigned)d.z >> 10, c3 = (unsigned)d.w >> 10;
        unsigned p0 = lbase[c0] + r0, p1 = lbase[c1] + r1;
        unsigned p2 = lbase[c2] + r2, p3 = lbase[c3] + r3;
        sval[p0] = (unsigned long long)((unsigned)s.x | (((unsigned)d.x & 1023u) << 20))
                 | ((unsigned long long)(e + 0u) << 32);
        sadr[p0] = gbs[c0] + r0;
        sval[p1] = (unsigned long long)((unsigned)s.y | (((unsigned)d.y & 1023u) << 20))
                 | ((unsigned long long)(e + 1u) << 32);
        sadr[p1] = gbs[c1] + r1;
        sval[p2] = (unsigned long long)((unsigned)s.z | (((unsigned)d.z & 1023u) << 20))
                 | ((unsigned long long)(e + 2u) << 32);
        sadr[p2] = gbs[c2] + r2;
        sval[p3] = (unsigned long long)((unsigned)s.w | (((unsigned)d.w & 1023u) << 20))
                 | ((unsigned long long)(e + 3u) << 32);
        sadr[p3] = gbs[c3] + r3;
    }
    __syncthreads();

    for (unsigned i = tid; i < tot; i += 256u)
        csr_pack[sadr[i]] = sval[i];
}

// ---------------------------------------------------------------------------
// K4: per-chunk CSR build (unchanged from R7): coalesced read, LDS ranks,
// LDS scan -> off, in-place permute within the chunk's L2-resident region.
// ---------------------------------------------------------------------------
__global__ __launch_bounds__(1024) void chunk_build(
    const unsigned* __restrict__ ctot, const unsigned* __restrict__ cbase,
    unsigned* __restrict__ off, unsigned long long* __restrict__ csr_pack)
{
    __shared__ unsigned cnt[1024];
    __shared__ unsigned ws[16];
    int t = threadIdx.x, c = blockIdx.x;

    unsigned base = cbase[c];
    unsigned ne   = ctot[c];
    cnt[t] = 0u;
    __syncthreads();

    unsigned long long ev[K_E];
    unsigned rk[K_E];
    #pragma unroll
    for (int k = 0; k < K_E; ++k) {
        unsigned i = (unsigned)t + (unsigned)k * 1024u;
        if (i < ne) {
            ev[k] = csr_pack[base + i];
            rk[k] = atomicAdd(&cnt[(unsigned)(ev[k] >> 20) & 1023u], 1u);
        }
    }
    __syncthreads();

    unsigned v = cnt[t];
    unsigned x = v;
    #pragma unroll
    for (int o = 1; o < 64; o <<= 1) {
        unsigned u = __shfl_up(x, o);
        if ((t & 63) >= o) x += u;
    }
    if ((t & 63) == 63) ws[t >> 6] = x;
    __syncthreads();
    if (t < 16) {
        unsigned y = ws[t];
        #pragma unroll
        for (int o = 1; o < 16; o <<= 1) {
            unsigned u = __shfl_up(y, o);
            if (t >= o) y += u;
        }
        ws[t] = y;
    }
    __syncthreads();
    unsigned excl = ((t >> 6) ? ws[(t >> 6) - 1] : 0u) + x - v;

    int gnode = c * 1024 + t;
    if (gnode < N_NODES) off[gnode] = base + excl;
    if (c == NCHUNK - 1 && t == 0) off[N_NODES] = N_EDGES;

    __syncthreads();
    cnt[t] = base + excl;
    __syncthreads();

    #pragma unroll
    for (int k = 0; k < K_E; ++k) {
        unsigned i = (unsigned)t + (unsigned)k * 1024u;
        if (i < ne) {
            unsigned dl = (unsigned)(ev[k] >> 20) & 1023u;
            csr_pack[cnt[dl] + rk[k]] = ev[k] & 0xFFFFFFFF000FFFFFull;
        }
    }
}

// ---------------------------------------------------------------------------
// Gather v3: TWO nodes per wave (grid 12500 x 8 waves x 2 = 100000 exact).
// Two independent dependent-chains per wave double in-flight loads (the
// kernel was latency-bound: VALU 37%, HBM 28%, no pipe saturated). We/bias
// loads deferred to the epilogue to keep main-loop VGPR < 64 (occupancy).
// ---------------------------------------------------------------------------
__device__ __forceinline__ float node_finish(
    float gh4[4], float ae4[4], int ln, const float* We)
{
    #pragma unroll
    for (int c = 0; c < 4; ++c) {
        gh4[c] += __shfl_xor(gh4[c], 16);
        gh4[c] += __shfl_xor(gh4[c], 32);
        ae4[c] += __shfl_xor(ae4[c], 4);
        ae4[c] += __shfl_xor(ae4[c], 8);
        ae4[c] += __shfl_xor(ae4[c], 16);
        ae4[c] += __shfl_xor(ae4[c], 32);
    }
    int srcl = ln >> 2;
    float r0 = __shfl(gh4[0], srcl);
    float r1 = __shfl(gh4[1], srcl);
    float r2 = __shfl(gh4[2], srcl);
    float r3 = __shfl(gh4[3], srcl);
    int c = ln & 3;
    float acc = (c & 2) ? ((c & 1) ? r3 : r2) : ((c & 1) ? r1 : r0);
    #pragma unroll
    for (int k = 0; k < 16; ++k)
        acc = fmaf(__shfl(ae4[k & 3], k >> 2), We[k], acc);
    return acc;
}

__global__ __launch_bounds__(256) void gather_out(
    const unsigned short* __restrict__ G,
    const float* __restrict__ edge_feats,
    const unsigned long long* __restrict__ csr_pack,
    const unsigned* __restrict__ off,
    const float* __restrict__ weight,   // rows 0..15 = W_e
    const float* __restrict__ bias,
    float* __restrict__ out)
{
    int tid = threadIdx.x;
    int wv = tid >> 6, ln = tid & 63;

    const float SC = 1.0507009873554805f;
    const float AL = 1.6732632423543772f;

    const int gq = ln >> 4;
    const int eq = ln >> 2;
    const ushort4* __restrict__ Gv = (const ushort4*)G;

    int nA = blockIdx.x * 8 + wv * 2;   // nB = nA + 1; both < N_NODES (exact grid)
    unsigned o0 = off[nA], o1 = off[nA + 1], o2 = off[nA + 2];

    float ghA[4] = {0.f,0.f,0.f,0.f}, aeA[4] = {0.f,0.f,0.f,0.f};
    float ghB[4] = {0.f,0.f,0.f,0.f}, aeB[4] = {0.f,0.f,0.f,0.f};

    unsigned baseA = o0, baseB = o1;
    while (baseA < o1 || baseB < o2) {
        unsigned mA = (baseA < o1) ? min(64u, o1 - baseA) : 0u;
        unsigned mB = (baseB < o2) ? min(64u, o2 - baseB) : 0u;
        unsigned loA = 0u, hiA = 0u, loB = 0u, hiB = 0u;
        if ((unsigned)ln < mA) {
            unsigned long long pk = csr_pack[baseA + (unsigned)ln];
            loA = (unsigned)pk; hiA = (unsigned)(pk >> 32);
        }
        if ((unsigned)ln < mB) {
            unsigned long long pk = csr_pack[baseB + (unsigned)ln];
            loB = (unsigned)pk; hiB = (unsigned)(pk >> 32);
        }
        unsigned mm = mA > mB ? mA : mB;

        for (unsigned i = 0; i < mm; i += 8u) {
            if (i < mA) {
                unsigned i0 = i + (unsigned)gq, i1 = i0 + 4u;
                unsigned s0 = __shfl(loA, (int)min(i0, mA - 1u));
                unsigned s1 = __shfl(loA, (int)min(i1, mA - 1u));
                ushort4 q0 = {0,0,0,0}, q1 = {0,0,0,0};
                if (i0 < mA) q0 = Gv[(size_t)s0 * 16u + (unsigned)(ln & 15)];
                if (i1 < mA) q1 = Gv[(size_t)s1 * 16u + (unsigned)(ln & 15)];
                ghA[0] += __uint_as_float((unsigned)q0.x << 16) + __uint_as_float((unsigned)q1.x << 16);
                ghA[1] += __uint_as_float((unsigned)q0.y << 16) + __uint_as_float((unsigned)q1.y << 16);
                ghA[2] += __uint_as_float((unsigned)q0.z << 16) + __uint_as_float((unsigned)q1.z << 16);
                ghA[3] += __uint_as_float((unsigned)q0.w << 16) + __uint_as_float((unsigned)q1.w << 16);
            }
            if (i < mB) {
                unsigned i0 = i + (unsigned)gq, i1 = i0 + 4u;
                unsigned s0 = __shfl(loB, (int)min(i0, mB - 1u));
                unsigned s1 = __shfl(loB, (int)min(i1, mB - 1u));
                ushort4 q0 = {0,0,0,0}, q1 = {0,0,0,0};
                if (i0 < mB) q0 = Gv[(size_t)s0 * 16u + (unsigned)(ln & 15)];
                if (i1 < mB) q1 = Gv[(size_t)s1 * 16u + (unsigned)(ln & 15)];
                ghB[0] += __uint_as_float((unsigned)q0.x << 16) + __uint_as_float((unsigned)q1.x << 16);
                ghB[1] += __uint_as_float((unsigned)q0.y << 16) + __uint_as_float((unsigned)q1.y << 16);
                ghB[2] += __uint_as_float((unsigned)q0.z << 16) + __uint_as_float((unsigned)q1.z << 16);
                ghB[3] += __uint_as_float((unsigned)q0.w << 16) + __uint_as_float((unsigned)q1.w << 16);
            }
        }

        for (unsigned i = 0; i < mm; i += 16u) {
            if (i < mA) {
                unsigned ie = i + (unsigned)eq;
                unsigned e0 = __shfl(hiA, (int)min(ie, mA - 1u));
                if (ie < mA) {
                    float4 v = *(const float4*)(edge_feats + (size_t)e0 * 16u + (unsigned)(ln & 3) * 4u);
                    aeA[0] += v.x; aeA[1] += v.y; aeA[2] += v.z; aeA[3] += v.w;
                }
            }
            if (i < mB) {
                unsigned ie = i + (unsigned)eq;
                unsigned e0 = __shfl(hiB, (int)min(ie, mB - 1u));
                if (ie < mB) {
                    float4 v = *(const float4*)(edge_feats + (size_t)e0 * 16u + (unsigned)(ln & 3) * 4u);
                    aeB[0] += v.x; aeB[1] += v.y; aeB[2] += v.z; aeB[3] += v.w;
                }
            }
        }
        baseA += 64u; baseB += 64u;
    }

    // ---- epilogue (We/bias loaded late to cap main-loop VGPR) ----
    float We[16];
    #pragma unroll
    for (int k = 0; k < 16; ++k) We[k] = weight[k * 64 + ln];
    float b = bias[ln];

    float normA = __builtin_amdgcn_rcpf(fmaxf((float)(o1 - o0), 1.0f));
    float normB = __builtin_amdgcn_rcpf(fmaxf((float)(o2 - o1), 1.0f));

    float accA = node_finish(ghA, aeA, ln, We);
    float accB = node_finish(ghB, aeB, ln, We);

    float oA = accA * normA + b;
    float oB = accB * normB + b;
    out[(size_t)nA * 64u + ln]       = (oA > 0.f) ? SC * oA : SC * AL * (__expf(oA) - 1.0f);
    out[(size_t)(nA + 1) * 64u + ln] = (oB > 0.f) ? SC * oB : SC * AL * (__expf(oB) - 1.0f);
}

extern "C" void kernel_launch(void* const* d_in, const int* in_sizes, int n_in,
                              void* d_out, int out_size, void* d_ws, size_t ws_size,
                              hipStream_t stream) {
    const float* feat       = (const float*)d_in[0];
    const float* edge_feats = (const float*)d_in[1];
    const int*   src        = (const int*)d_in[2];
    const int*   dst        = (const int*)d_in[3];
    const float* weight     = (const float*)d_in[4];
    const float* bias       = (const float*)d_in[5];
    float* out = (float*)d_out;

    // ws: csr_pack | G | off | pcnt | pbase | ctot | cbase | done
    unsigned long long* csr_pack = (unsigned long long*)d_ws;
    unsigned short* G = (unsigned short*)(csr_pack + N_EDGES);
    unsigned* off   = (unsigned*)(G + (size_t)N_NODES * 64);    // N_NODES + 1
    unsigned* pcnt  = off + N_NODES + 1;                        // CNT_BLK*NCHUNK
    unsigned* pbase = pcnt + (size_t)CNT_BLK * NCHUNK;          // CNT_BLK*NCHUNK
    unsigned* ctot  = pbase + (size_t)CNT_BLK * NCHUNK;         // NCHUNK
    unsigned* cbase = ctot + NCHUNK;                            // NCHUNK
    unsigned* done  = cbase + NCHUNK;                           // 1

    count_gemm<<<dim3(CNT_BLK + GEMM_BLK), dim3(256), 0, stream>>>(
        dst, pcnt, feat, weight, G, done);
    colscan_cbase<<<dim3(NCHUNK), dim3(1024), 0, stream>>>(
        pcnt, pbase, ctot, cbase, done);
    scatter<<<dim3(CNT_BLK), dim3(256), 0, stream>>>(
        src, dst, pbase, cbase, csr_pack);
    chunk_build<<<dim3(NCHUNK), dim3(1024), 0, stream>>>(
        ctot, cbase, off, csr_pack);
    gather_out<<<dim3(N_NODES / 8), dim3(256), 0, stream>>>(
        G, edge_feats, csr_pack, off, weight, bias, out);
}